// Round 1
// baseline (934.201 us; speedup 1.0000x reference)
//
#include <hip/hip_runtime.h>
#include <hip/hip_bf16.h>
#include <stdint.h>

// Problem dims (fixed by the reference)
constexpr int kB = 32;
constexpr int kS = 1024;
constexpr int kDin = 1024;
constexpr int kDout = 4096;
constexpr int kRank = 16;
constexpr int kNAdapt = 8;
constexpr int kM = kB * kS;     // 32768 rows
constexpr float kScale = 2.0f;  // alpha/rank = 32/16

typedef __attribute__((ext_vector_type(4))) float f32x4;
typedef __attribute__((ext_vector_type(8))) short s16x8;
typedef __attribute__((ext_vector_type(8))) unsigned short u16x8;
typedef __attribute__((ext_vector_type(4))) unsigned short u16x4;

__device__ __forceinline__ unsigned short f2bf(float f) {
  union { float f; uint32_t u; } x; x.f = f;
  uint32_t u = x.u;
  u += 0x7fffu + ((u >> 16) & 1u);   // round-to-nearest-even
  return (unsigned short)(u >> 16);
}

// ---------- Kernel 1: cast hidden_states f32 -> bf16 (vectorized 8/thread) ----------
__global__ void cast_h_kernel(const float* __restrict__ h, unsigned short* __restrict__ out) {
  size_t i = (size_t)blockIdx.x * blockDim.x + threadIdx.x;
  const f32x4* src = reinterpret_cast<const f32x4*>(h) + i * 2;
  f32x4 v0 = src[0], v1 = src[1];
  u16x8 r;
  r[0] = f2bf(v0[0]); r[1] = f2bf(v0[1]); r[2] = f2bf(v0[2]); r[3] = f2bf(v0[3]);
  r[4] = f2bf(v1[0]); r[5] = f2bf(v1[1]); r[6] = f2bf(v1[2]); r[7] = f2bf(v1[3]);
  *reinterpret_cast<u16x8*>(out + i * 8) = r;
}

// ---------- Kernel 2: W_eff^T[e][o][d] = W[d][o] + 2 * sum_r la[e][d][r]*lb[e][r][o]
// One block per (e,o): 256 threads cover d in chunks of 4. Writes are fully
// coalesced along d (the GEMM's K axis); W column reads are L2/LLC-absorbed.
__global__ void build_weff_kernel(const float* __restrict__ W,
                                  const float* __restrict__ la,
                                  const float* __restrict__ lb,
                                  unsigned short* __restrict__ weff) {
  int e = blockIdx.x >> 12;          // / 4096
  int o = blockIdx.x & (kDout - 1);
  float bv[kRank];
#pragma unroll
  for (int r = 0; r < kRank; ++r)
    bv[r] = kScale * lb[((size_t)e * kRank + r) * kDout + o];
  int d0 = threadIdx.x * 4;
  u16x4 r4;
#pragma unroll
  for (int j = 0; j < 4; ++j) {
    int d = d0 + j;
    float s = W[(size_t)d * kDout + o];
    const f32x4* ar = reinterpret_cast<const f32x4*>(la + ((size_t)e * kDin + d) * kRank);
#pragma unroll
    for (int q = 0; q < 4; ++q) {
      f32x4 a4 = ar[q];
      s += bv[q * 4 + 0] * a4[0] + bv[q * 4 + 1] * a4[1] +
           bv[q * 4 + 2] * a4[2] + bv[q * 4 + 3] * a4[3];
    }
    r4[j] = f2bf(s);
  }
  *reinterpret_cast<u16x4*>(weff + ((size_t)e * kDout + o) * kDin + d0) = r4;
}

// ---------- Kernel 3: grouped GEMM out = h_bf16 @ W_eff[aid]^T + bias ----------
// m97 structure: 128x128 tile, BK=32, 4 waves (2x2), 16x16x32 bf16 MFMA,
// global_load_lds width-16 staging, 2-barrier K-loop, XCD-bijective swizzle.
constexpr int BM = 128, BN = 128, BK = 32;
constexpr int MT = kM / BM;      // 256
constexpr int NT = kDout / BN;   // 32
constexpr int NWG = MT * NT;     // 8192 (divisible by 8 -> simple swizzle OK)

__device__ __forceinline__ void gload_lds16(const unsigned short* g, unsigned short* l) {
  __builtin_amdgcn_global_load_lds((const __attribute__((address_space(1))) void*)g,
                                   (__attribute__((address_space(3))) void*)l, 16, 0, 0);
}

__global__ __launch_bounds__(256) void gemm_kernel(
    const unsigned short* __restrict__ Ab,    // [M][K] bf16
    const unsigned short* __restrict__ Weff,  // [NA][N][K] bf16 (transposed)
    const float* __restrict__ bias,
    const int* __restrict__ aids,
    float* __restrict__ out) {
  __shared__ unsigned short As[BM * BK];   // 8 KiB, [row][k] row-major
  __shared__ unsigned short Bs[BN * BK];   // 8 KiB, [col][k] row-major
  int bid = blockIdx.x;
  int swz = (bid & 7) * (NWG / 8) + (bid >> 3);   // XCD-aware, bijective
  int mt = swz / NT, nt = swz % NT;
  int aid = aids[mt >> 3];   // BM=128 divides S=1024 -> one sample per M-tile
  const unsigned short* Aptr = Ab + (size_t)mt * BM * kDin;
  const unsigned short* Bptr = Weff + ((size_t)aid * kDout + (size_t)nt * BN) * kDin;
  int t = threadIdx.x;
  int l = t & 63;
  int w = t >> 6;
  int wr = w >> 1, wc = w & 1;   // 2x2 waves, each owns 64x64

  // staging: thread t, chunk c in {0,1}: row = c*64 + t/4, k-sub = (t&3)*8
  // -> LDS byte offset c*4096 + t*16 (linear: matches global_load_lds semantics)
  const unsigned short* ga = Aptr + (size_t)(t >> 2) * kDin + (t & 3) * 8;
  const unsigned short* gb = Bptr + (size_t)(t >> 2) * kDin + (t & 3) * 8;
  unsigned short* lA = &As[t * 8];
  unsigned short* lB = &Bs[t * 8];

  f32x4 acc[4][4];
#pragma unroll
  for (int m = 0; m < 4; ++m)
#pragma unroll
    for (int n = 0; n < 4; ++n) acc[m][n] = f32x4{0.f, 0.f, 0.f, 0.f};

  int arow = wr * 64 + (l & 15);
  int brow = wc * 64 + (l & 15);
  int kf = (l >> 4) * 8;   // A/B frag: 8 contiguous k at group (lane>>4)

  for (int k0 = 0; k0 < kDin; k0 += BK) {
    gload_lds16(ga + k0, lA);
    gload_lds16(ga + (size_t)64 * kDin + k0, lA + 2048);
    gload_lds16(gb + k0, lB);
    gload_lds16(gb + (size_t)64 * kDin + k0, lB + 2048);
    __syncthreads();   // compiler emits vmcnt(0) drain before barrier
    s16x8 af[4], bf[4];
#pragma unroll
    for (int m = 0; m < 4; ++m)
      af[m] = *reinterpret_cast<const s16x8*>(&As[(arow + m * 16) * BK + kf]);
#pragma unroll
    for (int n = 0; n < 4; ++n)
      bf[n] = *reinterpret_cast<const s16x8*>(&Bs[(brow + n * 16) * BK + kf]);
#pragma unroll
    for (int m = 0; m < 4; ++m)
#pragma unroll
      for (int n = 0; n < 4; ++n)
        acc[m][n] = __builtin_amdgcn_mfma_f32_16x16x32_bf16(af[m], bf[n], acc[m][n], 0, 0, 0);
    __syncthreads();
  }

  // Epilogue: C/D layout col = lane&15, row = (lane>>4)*4 + reg (m89-verified)
  int row0 = mt * BM + wr * 64 + (l >> 4) * 4;
  int col0 = nt * BN + wc * 64 + (l & 15);
#pragma unroll
  for (int n = 0; n < 4; ++n) {
    float bv = bias[col0 + n * 16];
#pragma unroll
    for (int m = 0; m < 4; ++m) {
#pragma unroll
      for (int j = 0; j < 4; ++j)
        out[(size_t)(row0 + m * 16 + j) * kDout + (col0 + n * 16)] = acc[m][n][j] + bv;
    }
  }
}

extern "C" void kernel_launch(void* const* d_in, const int* in_sizes, int n_in,
                              void* d_out, int out_size, void* d_ws, size_t ws_size,
                              hipStream_t stream) {
  const float* h    = (const float*)d_in[0];   // [32,1024,1024] f32
  const int*   aids = (const int*)d_in[1];     // [32] i32
  const float* W    = (const float*)d_in[2];   // [1024,4096] f32
  const float* bias = (const float*)d_in[3];   // [4096] f32
  const float* la   = (const float*)d_in[4];   // [8,1024,16] f32
  const float* lb   = (const float*)d_in[5];   // [8,16,4096] f32
  float* out = (float*)d_out;                  // [32,1024,4096] f32

  // workspace: h_bf16 (64 MiB) + W_eff^T (64 MiB) = 128 MiB
  unsigned short* Abf  = (unsigned short*)d_ws;
  unsigned short* Weff = Abf + (size_t)kM * kDin;

  cast_h_kernel<<<(kM * (size_t)kDin / 8) / 256, 256, 0, stream>>>(h, Abf);
  build_weff_kernel<<<kNAdapt * kDout, 256, 0, stream>>>(W, la, lb, Weff);
  gemm_kernel<<<NWG, 256, 0, stream>>>(Abf, Weff, bias, aids, out);
}

// Round 2
// 510.364 us; speedup vs baseline: 1.8305x; 1.8305x over previous
//
#include <hip/hip_runtime.h>
#include <hip/hip_bf16.h>
#include <stdint.h>

// Problem dims (fixed by the reference)
constexpr int kB = 32;
constexpr int kS = 1024;
constexpr int kDin = 1024;
constexpr int kDout = 4096;
constexpr int kRank = 16;
constexpr int kNAdapt = 8;
constexpr int kM = kB * kS;     // 32768 rows
constexpr float kScale = 2.0f;  // alpha/rank = 32/16

typedef __attribute__((ext_vector_type(4))) float f32x4;
typedef __attribute__((ext_vector_type(8))) short s16x8;
typedef __attribute__((ext_vector_type(8))) unsigned short u16x8;
typedef __attribute__((ext_vector_type(4))) unsigned short u16x4;

__device__ __forceinline__ unsigned short f2bf(float f) {
  union { float f; uint32_t u; } x; x.f = f;
  uint32_t u = x.u;
  u += 0x7fffu + ((u >> 16) & 1u);   // round-to-nearest-even
  return (unsigned short)(u >> 16);
}

// ---------- Kernel 1: cast hidden_states f32 -> bf16 (vectorized 8/thread) ----------
__global__ void cast_h_kernel(const float* __restrict__ h, unsigned short* __restrict__ out) {
  size_t i = (size_t)blockIdx.x * blockDim.x + threadIdx.x;
  const f32x4* src = reinterpret_cast<const f32x4*>(h) + i * 2;
  f32x4 v0 = src[0], v1 = src[1];
  u16x8 r;
  r[0] = f2bf(v0[0]); r[1] = f2bf(v0[1]); r[2] = f2bf(v0[2]); r[3] = f2bf(v0[3]);
  r[4] = f2bf(v1[0]); r[5] = f2bf(v1[1]); r[6] = f2bf(v1[2]); r[7] = f2bf(v1[3]);
  *reinterpret_cast<u16x8*>(out + i * 8) = r;
}

// ---------- Kernel 2 (rewritten): LDS-tiled transpose + rank-16 update ----------
// Weff^T[e][o][d] = W[d][o] + 2 * sum_r la[e][d][r]*lb[e][r][o]
// Block = one 64(d) x 64(o) tile for one adapter e. W read coalesced along o,
// write coalesced along d (16 lanes x 8B contiguous). e is the fastest grid
// dim so 8 consecutive blocks reuse the same W tile from L2/LLC.
__global__ __launch_bounds__(256) void build_weff_kernel(
    const float* __restrict__ W,
    const float* __restrict__ la,
    const float* __restrict__ lb,
    unsigned short* __restrict__ weff) {
  __shared__ float Wt[64][68];   // pad 68: 16B-aligned b128 stores, 2-way max on reads
  __shared__ float At[64][20];   // la tile [d][r], pad 20
  __shared__ float Bt[16][68];   // lb tile [r][o]
  int bid = blockIdx.x;
  int e = bid & 7;
  int rem = bid >> 3;            // 0..1023
  int dt = rem >> 6;             // 0..15
  int ot = rem & 63;             // 0..63
  int d0 = dt * 64, o0 = ot * 64;
  int t = threadIdx.x;

  // load W tile: 4 passes; thread t: row = p*16 + t/16, col = 4*(t%16)
  {
    int r = t >> 4;
    int c = (t & 15) * 4;
    const float* wp = W + (size_t)(d0 + r) * kDout + o0 + c;
#pragma unroll
    for (int p = 0; p < 4; ++p) {
      f32x4 v = *reinterpret_cast<const f32x4*>(wp + (size_t)p * 16 * kDout);
      *reinterpret_cast<f32x4*>(&Wt[p * 16 + r][c]) = v;
    }
  }
  // load la tile: thread t -> d = t/4, r4 = (t%4)*4
  {
    int d = t >> 2, r4 = (t & 3) * 4;
    f32x4 v = *reinterpret_cast<const f32x4*>(la + ((size_t)e * kDin + d0 + d) * kRank + r4);
    *reinterpret_cast<f32x4*>(&At[d][r4]) = v;
  }
  // load lb tile: thread t -> r = t/16, c = 4*(t%16)
  {
    int r = t >> 4, c = (t & 15) * 4;
    f32x4 v = *reinterpret_cast<const f32x4*>(lb + ((size_t)e * kRank + r) * kDout + o0 + c);
    *reinterpret_cast<f32x4*>(&Bt[r][c]) = v;
  }
  __syncthreads();

  // thread t owns d_local = 4*(t%16)..+3 for o_local = p*16 + t/16, p=0..3
  int ol_base = t >> 4;
  int dl = (t & 15) * 4;
  // hoist la rows for the 4 owned d into registers (reused across 4 passes)
  f32x4 areg[4][4];
#pragma unroll
  for (int j = 0; j < 4; ++j)
#pragma unroll
    for (int q = 0; q < 4; ++q)
      areg[j][q] = *reinterpret_cast<const f32x4*>(&At[dl + j][q * 4]);

#pragma unroll
  for (int p = 0; p < 4; ++p) {
    int ol = p * 16 + ol_base;
    float bv[kRank];
#pragma unroll
    for (int r = 0; r < kRank; ++r) bv[r] = Bt[r][ol];   // broadcast across 16 lanes
    u16x4 r4;
#pragma unroll
    for (int j = 0; j < 4; ++j) {
      float acc = 0.f;
#pragma unroll
      for (int q = 0; q < 4; ++q)
        acc += areg[j][q][0] * bv[q * 4 + 0] + areg[j][q][1] * bv[q * 4 + 1] +
               areg[j][q][2] * bv[q * 4 + 2] + areg[j][q][3] * bv[q * 4 + 3];
      r4[j] = f2bf(Wt[dl + j][ol] + kScale * acc);
    }
    *reinterpret_cast<u16x4*>(weff + ((size_t)e * kDout + o0 + ol) * kDin + d0 + dl) = r4;
  }
}

// ---------- Kernel 3: grouped GEMM out = h_bf16 @ W_eff[aid]^T + bias ----------
// m97 structure: 128x128 tile, BK=32, 4 waves (2x2), 16x16x32 bf16 MFMA,
// global_load_lds width-16 staging, 2-barrier K-loop, XCD-bijective swizzle.
constexpr int BM = 128, BN = 128, BK = 32;
constexpr int MT = kM / BM;      // 256
constexpr int NT = kDout / BN;   // 32
constexpr int NWG = MT * NT;     // 8192 (divisible by 8 -> simple swizzle OK)

__device__ __forceinline__ void gload_lds16(const unsigned short* g, unsigned short* l) {
  __builtin_amdgcn_global_load_lds((const __attribute__((address_space(1))) void*)g,
                                   (__attribute__((address_space(3))) void*)l, 16, 0, 0);
}

__global__ __launch_bounds__(256) void gemm_kernel(
    const unsigned short* __restrict__ Ab,    // [M][K] bf16
    const unsigned short* __restrict__ Weff,  // [NA][N][K] bf16 (transposed)
    const float* __restrict__ bias,
    const int* __restrict__ aids,
    float* __restrict__ out) {
  __shared__ unsigned short As[BM * BK];   // 8 KiB, [row][k] row-major
  __shared__ unsigned short Bs[BN * BK];   // 8 KiB, [col][k] row-major
  int bid = blockIdx.x;
  int swz = (bid & 7) * (NWG / 8) + (bid >> 3);   // XCD-aware, bijective
  int mt = swz / NT, nt = swz % NT;
  int aid = aids[mt >> 3];   // BM=128 divides S=1024 -> one sample per M-tile
  const unsigned short* Aptr = Ab + (size_t)mt * BM * kDin;
  const unsigned short* Bptr = Weff + ((size_t)aid * kDout + (size_t)nt * BN) * kDin;
  int t = threadIdx.x;
  int l = t & 63;
  int w = t >> 6;
  int wr = w >> 1, wc = w & 1;   // 2x2 waves, each owns 64x64

  const unsigned short* ga = Aptr + (size_t)(t >> 2) * kDin + (t & 3) * 8;
  const unsigned short* gb = Bptr + (size_t)(t >> 2) * kDin + (t & 3) * 8;
  unsigned short* lA = &As[t * 8];
  unsigned short* lB = &Bs[t * 8];

  f32x4 acc[4][4];
#pragma unroll
  for (int m = 0; m < 4; ++m)
#pragma unroll
    for (int n = 0; n < 4; ++n) acc[m][n] = f32x4{0.f, 0.f, 0.f, 0.f};

  int arow = wr * 64 + (l & 15);
  int brow = wc * 64 + (l & 15);
  int kf = (l >> 4) * 8;

  for (int k0 = 0; k0 < kDin; k0 += BK) {
    gload_lds16(ga + k0, lA);
    gload_lds16(ga + (size_t)64 * kDin + k0, lA + 2048);
    gload_lds16(gb + k0, lB);
    gload_lds16(gb + (size_t)64 * kDin + k0, lB + 2048);
    __syncthreads();
    s16x8 af[4], bf[4];
#pragma unroll
    for (int m = 0; m < 4; ++m)
      af[m] = *reinterpret_cast<const s16x8*>(&As[(arow + m * 16) * BK + kf]);
#pragma unroll
    for (int n = 0; n < 4; ++n)
      bf[n] = *reinterpret_cast<const s16x8*>(&Bs[(brow + n * 16) * BK + kf]);
#pragma unroll
    for (int m = 0; m < 4; ++m)
#pragma unroll
      for (int n = 0; n < 4; ++n)
        acc[m][n] = __builtin_amdgcn_mfma_f32_16x16x32_bf16(af[m], bf[n], acc[m][n], 0, 0, 0);
    __syncthreads();
  }

  // Epilogue: C/D layout col = lane&15, row = (lane>>4)*4 + reg (m89-verified)
  int row0 = mt * BM + wr * 64 + (l >> 4) * 4;
  int col0 = nt * BN + wc * 64 + (l & 15);
#pragma unroll
  for (int n = 0; n < 4; ++n) {
    float bv = bias[col0 + n * 16];
#pragma unroll
    for (int m = 0; m < 4; ++m) {
#pragma unroll
      for (int j = 0; j < 4; ++j)
        out[(size_t)(row0 + m * 16 + j) * kDout + (col0 + n * 16)] = acc[m][n][j] + bv;
    }
  }
}

extern "C" void kernel_launch(void* const* d_in, const int* in_sizes, int n_in,
                              void* d_out, int out_size, void* d_ws, size_t ws_size,
                              hipStream_t stream) {
  const float* h    = (const float*)d_in[0];   // [32,1024,1024] f32
  const int*   aids = (const int*)d_in[1];     // [32] i32
  const float* W    = (const float*)d_in[2];   // [1024,4096] f32
  const float* bias = (const float*)d_in[3];   // [4096] f32
  const float* la   = (const float*)d_in[4];   // [8,1024,16] f32
  const float* lb   = (const float*)d_in[5];   // [8,16,4096] f32
  float* out = (float*)d_out;                  // [32,1024,4096] f32

  // workspace: h_bf16 (64 MiB) + W_eff^T (64 MiB) = 128 MiB
  unsigned short* Abf  = (unsigned short*)d_ws;
  unsigned short* Weff = Abf + (size_t)kM * kDin;

  cast_h_kernel<<<(kM * (size_t)kDin / 8) / 256, 256, 0, stream>>>(h, Abf);
  build_weff_kernel<<<kNAdapt * (kDin / 64) * (kDout / 64), 256, 0, stream>>>(W, la, lb, Weff);
  gemm_kernel<<<NWG, 256, 0, stream>>>(Abf, Weff, bias, aids, out);
}

// Round 3
// 460.675 us; speedup vs baseline: 2.0279x; 1.1079x over previous
//
#include <hip/hip_runtime.h>
#include <hip/hip_bf16.h>
#include <stdint.h>

// Problem dims (fixed by the reference)
constexpr int kB = 32;
constexpr int kS = 1024;
constexpr int kDin = 1024;
constexpr int kDout = 4096;
constexpr int kRank = 16;
constexpr int kNAdapt = 8;
constexpr int kM = kB * kS;     // 32768 rows
constexpr float kScale = 2.0f;  // alpha/rank = 32/16

typedef __attribute__((ext_vector_type(4))) float f32x4;
typedef __attribute__((ext_vector_type(8))) short s16x8;
typedef __attribute__((ext_vector_type(8))) unsigned short u16x8;
typedef __attribute__((ext_vector_type(4))) unsigned short u16x4;

__device__ __forceinline__ unsigned short f2bf(float f) {
  union { float f; uint32_t u; } x; x.f = f;
  uint32_t u = x.u;
  u += 0x7fffu + ((u >> 16) & 1u);   // round-to-nearest-even
  return (unsigned short)(u >> 16);
}

// ---------- Kernel 1: cast hidden_states f32 -> bf16 (vectorized 8/thread) ----------
__global__ void cast_h_kernel(const float* __restrict__ h, unsigned short* __restrict__ out) {
  size_t i = (size_t)blockIdx.x * blockDim.x + threadIdx.x;
  const f32x4* src = reinterpret_cast<const f32x4*>(h) + i * 2;
  f32x4 v0 = src[0], v1 = src[1];
  u16x8 r;
  r[0] = f2bf(v0[0]); r[1] = f2bf(v0[1]); r[2] = f2bf(v0[2]); r[3] = f2bf(v0[3]);
  r[4] = f2bf(v1[0]); r[5] = f2bf(v1[1]); r[6] = f2bf(v1[2]); r[7] = f2bf(v1[3]);
  *reinterpret_cast<u16x8*>(out + i * 8) = r;
}

// ---------- Kernel 2: LDS-tiled transpose + rank-16 update (R2, verified) ----------
__global__ __launch_bounds__(256) void build_weff_kernel(
    const float* __restrict__ W,
    const float* __restrict__ la,
    const float* __restrict__ lb,
    unsigned short* __restrict__ weff) {
  __shared__ float Wt[64][68];
  __shared__ float At[64][20];
  __shared__ float Bt[16][68];
  int bid = blockIdx.x;
  int e = bid & 7;
  int rem = bid >> 3;
  int dt = rem >> 6;
  int ot = rem & 63;
  int d0 = dt * 64, o0 = ot * 64;
  int t = threadIdx.x;
  {
    int r = t >> 4;
    int c = (t & 15) * 4;
    const float* wp = W + (size_t)(d0 + r) * kDout + o0 + c;
#pragma unroll
    for (int p = 0; p < 4; ++p) {
      f32x4 v = *reinterpret_cast<const f32x4*>(wp + (size_t)p * 16 * kDout);
      *reinterpret_cast<f32x4*>(&Wt[p * 16 + r][c]) = v;
    }
  }
  {
    int d = t >> 2, r4 = (t & 3) * 4;
    f32x4 v = *reinterpret_cast<const f32x4*>(la + ((size_t)e * kDin + d0 + d) * kRank + r4);
    *reinterpret_cast<f32x4*>(&At[d][r4]) = v;
  }
  {
    int r = t >> 4, c = (t & 15) * 4;
    f32x4 v = *reinterpret_cast<const f32x4*>(lb + ((size_t)e * kRank + r) * kDout + o0 + c);
    *reinterpret_cast<f32x4*>(&Bt[r][c]) = v;
  }
  __syncthreads();
  int ol_base = t >> 4;
  int dl = (t & 15) * 4;
  f32x4 areg[4][4];
#pragma unroll
  for (int j = 0; j < 4; ++j)
#pragma unroll
    for (int q = 0; q < 4; ++q)
      areg[j][q] = *reinterpret_cast<const f32x4*>(&At[dl + j][q * 4]);
#pragma unroll
  for (int p = 0; p < 4; ++p) {
    int ol = p * 16 + ol_base;
    float bv[kRank];
#pragma unroll
    for (int r = 0; r < kRank; ++r) bv[r] = Bt[r][ol];
    u16x4 r4;
#pragma unroll
    for (int j = 0; j < 4; ++j) {
      float acc = 0.f;
#pragma unroll
      for (int q = 0; q < 4; ++q)
        acc += areg[j][q][0] * bv[q * 4 + 0] + areg[j][q][1] * bv[q * 4 + 1] +
               areg[j][q][2] * bv[q * 4 + 2] + areg[j][q][3] * bv[q * 4 + 3];
      r4[j] = f2bf(Wt[dl + j][ol] + kScale * acc);
    }
    *reinterpret_cast<u16x4*>(weff + ((size_t)e * kDout + o0 + ol) * kDin + d0 + dl) = r4;
  }
}

// ---------- Kernel 3: 256x256 8-phase grouped GEMM (T1+T2+T3+T4+T5) ----------
constexpr int BM = 256, BN = 256, BK = 64;
constexpr int MT2 = kM / BM;      // 128
constexpr int NT2 = kDout / BN;   // 16
constexpr int NWG2 = MT2 * NT2;   // 2048 (divisible by 8)
constexpr int KT = kDin / BK;     // 16 K-tiles -> 8 iterations

__device__ __forceinline__ void gload16(const unsigned short* g, unsigned short* l) {
  __builtin_amdgcn_global_load_lds((const __attribute__((address_space(1))) void*)g,
                                   (__attribute__((address_space(3))) void*)l, 16, 0, 0);
}

// LDS element layout (unsigned short units):
//   slot*32768 + mat*16384 + half*8192 + instr*4096 + t*8
// logical (row r, elem c) of a [256][64] tile lives at physical
//   r*64 + (c ^ ((r&7)<<3))   (involution swizzle; source pre-swizzled)
#define STG_A(slot, h, kt) do { \
  gload16(gA + (size_t)((h) * 128) * kDin + (kt) * 64, ldst + (slot) * 32768 + (h) * 8192); \
  gload16(gA + (size_t)((h) * 128 + 64) * kDin + (kt) * 64, ldst + (slot) * 32768 + (h) * 8192 + 4096); \
} while (0)
#define STG_B(slot, h, kt) do { \
  gload16(gB + (size_t)((h) * 128) * kDin + (kt) * 64, ldst + (slot) * 32768 + 16384 + (h) * 8192); \
  gload16(gB + (size_t)((h) * 128 + 64) * kDin + (kt) * 64, ldst + (slot) * 32768 + 16384 + (h) * 8192 + 4096); \
} while (0)

#define RD_A(mh) do { _Pragma("unroll") for (int i = 0; i < 4; ++i) { \
  a[i][0] = *(const s16x8*)&lds[sBase + aRow + ((mh) * 4 + i) * 1024 + e0]; \
  a[i][1] = *(const s16x8*)&lds[sBase + aRow + ((mh) * 4 + i) * 1024 + e1]; } } while (0)
#define RD_B(nh, breg) do { _Pragma("unroll") for (int j = 0; j < 2; ++j) { \
  breg[j][0] = *(const s16x8*)&lds[sBase + bRow + ((nh) * 2 + j) * 1024 + e0]; \
  breg[j][1] = *(const s16x8*)&lds[sBase + bRow + ((nh) * 2 + j) * 1024 + e1]; } } while (0)

#define MM(mh, nh, breg) do { \
  __builtin_amdgcn_s_setprio(1); \
  _Pragma("unroll") for (int i = 0; i < 4; ++i) \
  _Pragma("unroll") for (int j = 0; j < 2; ++j) { \
    acc[(mh) * 4 + i][(nh) * 2 + j] = __builtin_amdgcn_mfma_f32_16x16x32_bf16( \
        a[i][0], breg[j][0], acc[(mh) * 4 + i][(nh) * 2 + j], 0, 0, 0); \
    acc[(mh) * 4 + i][(nh) * 2 + j] = __builtin_amdgcn_mfma_f32_16x16x32_bf16( \
        a[i][1], breg[j][1], acc[(mh) * 4 + i][(nh) * 2 + j], 0, 0, 0); } \
  __builtin_amdgcn_s_setprio(0); \
} while (0)

#define BAR1() do { __builtin_amdgcn_sched_barrier(0); __builtin_amdgcn_s_barrier(); \
  asm volatile("s_waitcnt lgkmcnt(0)" ::: "memory"); __builtin_amdgcn_sched_barrier(0); } while (0)
#define BAR2() do { __builtin_amdgcn_sched_barrier(0); __builtin_amdgcn_s_barrier(); } while (0)
#define VMC(n) asm volatile("s_waitcnt vmcnt(" #n ")" ::: "memory")

// One iteration = 2 K-tiles (slot0: tile 2i, slot1: tile 2i+1), 8 phases.
// Stage schedule (region-free proven, vmcnt(4) covers reads 2+ halves back):
//  ph1: rd s0 A(mh0)+B(nh0) | stg B1s1(2i+1)   ph5: rd s1 A(mh0)+B(nh0) | stg B1s0(2i+2)
//  ph2: rd s0 B(nh1)        | stg A1s1(2i+1)   ph6: rd s1 B(nh1)        | stg A1s0(2i+2)
//  ph3: rd s0 A(mh1)        | stg B0s0(2i+2)   ph7: rd s1 A(mh1)        | stg B0s1(2i+3)
//  ph4:                     | stg A0s0(2i+2) vmcnt(4)   ph8:            | stg A0s1(2i+3) vmcnt(4)
#define ITER(iv, LAST_) do { \
  int kt1 = 2 * (iv) + 1, kt2 = 2 * (iv) + 2, kt3 = 2 * (iv) + 3; \
  (void)kt2; (void)kt3; \
  { int sBase = 0; RD_A(0); RD_B(0, b0); } \
  STG_B(1, 1, kt1); \
  BAR1(); MM(0, 0, b0); BAR2(); \
  { int sBase = 0; RD_B(1, b1); } \
  STG_A(1, 1, kt1); \
  BAR1(); MM(0, 1, b1); BAR2(); \
  { int sBase = 0; RD_A(1); } \
  if (!LAST_) STG_B(0, 0, kt2); \
  BAR1(); MM(1, 0, b0); BAR2(); \
  if (!LAST_) { STG_A(0, 0, kt2); VMC(4); } else { VMC(0); } \
  BAR1(); MM(1, 1, b1); BAR2(); \
  { int sBase = 32768; RD_A(0); RD_B(0, b0); } \
  if (!LAST_) STG_B(0, 1, kt2); \
  BAR1(); MM(0, 0, b0); BAR2(); \
  { int sBase = 32768; RD_B(1, b1); } \
  if (!LAST_) STG_A(0, 1, kt2); \
  BAR1(); MM(0, 1, b1); BAR2(); \
  { int sBase = 32768; RD_A(1); } \
  if (!LAST_) STG_B(1, 0, kt3); \
  BAR1(); MM(1, 0, b0); BAR2(); \
  if (!LAST_) { STG_A(1, 0, kt3); VMC(4); } \
  BAR1(); MM(1, 1, b1); BAR2(); \
} while (0)

__global__ __launch_bounds__(512, 2) void gemm256_kernel(
    const unsigned short* __restrict__ Ab,    // [M][K] bf16
    const unsigned short* __restrict__ Weff,  // [NA][N][K] bf16
    const float* __restrict__ bias,
    const int* __restrict__ aids,
    float* __restrict__ out) {
  __shared__ unsigned short lds[65536];   // 128 KiB: [slot2][mat2][16384]
  int bid = blockIdx.x;
  int swz = (bid & 7) * (NWG2 / 8) + (bid >> 3);   // XCD-aware, bijective
  int mt = swz >> 4, nt = swz & 15;
  int aid = aids[mt >> 2];   // BM=256 divides S=1024: one sample per M-tile
  const unsigned short* Aptr = Ab + (size_t)mt * BM * kDin;
  const unsigned short* Bptr = Weff + ((size_t)aid * kDout + (size_t)nt * BN) * kDin;

  int t = threadIdx.x;
  int l = t & 63;
  int w = t >> 6;
  int wm = w >> 2;   // 0..1 (M), owns rows wm*128..+127
  int wn = w & 3;    // 0..3 (N), owns cols wn*64..+63

  // staging: thread t covers physical row t>>3 (per 64-row chunk), 16B col (t&7);
  // global source col is pre-swizzled so LDS stays linear (rule #21)
  int srcColEl = ((t & 7) * 8) ^ (((t >> 3) & 7) << 3);
  const unsigned short* gA = Aptr + (size_t)(t >> 3) * kDin + srcColEl;
  const unsigned short* gB = Bptr + (size_t)(t >> 3) * kDin + srcColEl;
  unsigned short* ldst = lds + t * 8;

  // fragment-read addressing (element units)
  int xmEl = (l & 7) << 3;                      // (row&7)<<3
  int e0 = (((l >> 4) * 8) ^ xmEl);             // kc=0 chunk
  int e1 = e0 ^ 32;                             // kc=1 chunk
  int aRow = (wm * 128 + (l & 15)) * 64;
  int bRow = (wn * 64 + (l & 15)) * 64 + 16384; // fold B-mat offset

  f32x4 acc[8][4];
#pragma unroll
  for (int m = 0; m < 8; ++m)
#pragma unroll
    for (int n = 0; n < 4; ++n) acc[m][n] = f32x4{0.f, 0.f, 0.f, 0.f};
  s16x8 a[4][2], b0[2][2], b1[2][2];

  // prologue: tile0 fully + tile1 B0,A0; first 8 loads must land
  STG_B(0, 0, 0); STG_A(0, 0, 0); STG_B(0, 1, 0); STG_A(0, 1, 0);
  STG_B(1, 0, 1); STG_A(1, 0, 1);
  VMC(4);
  BAR2();

  for (int i = 0; i < 7; ++i) ITER(i, false);
  ITER(7, true);

  // epilogue: C/D layout col = lane&15, row = (lane>>4)*4 + reg
  size_t row0 = (size_t)mt * BM + wm * 128 + (l >> 4) * 4;
  int col0 = nt * BN + wn * 64 + (l & 15);
#pragma unroll
  for (int nf = 0; nf < 4; ++nf) {
    float bv = bias[col0 + nf * 16];
#pragma unroll
    for (int mf = 0; mf < 8; ++mf) {
#pragma unroll
      for (int j = 0; j < 4; ++j)
        out[(row0 + mf * 16 + j) * kDout + col0 + nf * 16] = acc[mf][nf][j] + bv;
    }
  }
}

extern "C" void kernel_launch(void* const* d_in, const int* in_sizes, int n_in,
                              void* d_out, int out_size, void* d_ws, size_t ws_size,
                              hipStream_t stream) {
  const float* h    = (const float*)d_in[0];   // [32,1024,1024] f32
  const int*   aids = (const int*)d_in[1];     // [32] i32
  const float* W    = (const float*)d_in[2];   // [1024,4096] f32
  const float* bias = (const float*)d_in[3];   // [4096] f32
  const float* la   = (const float*)d_in[4];   // [8,1024,16] f32
  const float* lb   = (const float*)d_in[5];   // [8,16,4096] f32
  float* out = (float*)d_out;                  // [32,1024,4096] f32

  unsigned short* Abf  = (unsigned short*)d_ws;
  unsigned short* Weff = Abf + (size_t)kM * kDin;

  cast_h_kernel<<<(kM * (size_t)kDin / 8) / 256, 256, 0, stream>>>(h, Abf);
  build_weff_kernel<<<kNAdapt * (kDin / 64) * (kDout / 64), 256, 0, stream>>>(W, la, lb, Weff);
  gemm256_kernel<<<NWG2, 512, 0, stream>>>(Abf, Weff, bias, aids, out);
}